// Round 1
// baseline (4994.575 us; speedup 1.0000x reference)
//
#include <hip/hip_runtime.h>

#define HW 65536
#define SIDE 256

// ---------------------------------------------------------------------------
// Transpose h0 [N=65536][C=1024] -> X [C][N]
__global__ __launch_bounds__(256) void k_transpose_nc(const float* __restrict__ in,
                                                      float* __restrict__ out) {
  __shared__ float t[32][33];
  const int n0 = blockIdx.x << 5, c0 = blockIdx.y << 5;
  const int tx = threadIdx.x, ty = threadIdx.y;
#pragma unroll
  for (int r = 0; r < 32; r += 8)
    t[ty + r][tx] = in[(size_t)(n0 + ty + r) * 1024 + c0 + tx];
  __syncthreads();
#pragma unroll
  for (int r = 0; r < 32; r += 8)
    out[(size_t)(c0 + ty + r) * HW + n0 + tx] = t[tx][ty + r];
}

// ---------------------------------------------------------------------------
// Combine 7x7 + 5x5 + 3x3 depthwise weights + identity into one 7x7 kernel.
__global__ __launch_bounds__(256) void k_wcomb(const float* __restrict__ w7,
    const float* __restrict__ b7, const float* __restrict__ w5,
    const float* __restrict__ b5, const float* __restrict__ w3,
    const float* __restrict__ b3, float* __restrict__ wc, float* __restrict__ bc) {
  const int c = blockIdx.x * 256 + threadIdx.x;
  if (c >= 1024) return;
  float w[49];
#pragma unroll
  for (int i = 0; i < 49; i++) w[i] = w7[c * 49 + i];
  for (int dy = 0; dy < 5; dy++)
    for (int dx = 0; dx < 5; dx++)
      w[(dy + 1) * 7 + (dx + 1)] += w5[c * 25 + dy * 5 + dx];
  for (int dy = 0; dy < 3; dy++)
    for (int dx = 0; dx < 3; dx++)
      w[(dy + 2) * 7 + (dx + 2)] += w3[c * 9 + dy * 3 + dx];
  w[3 * 7 + 3] += 1.0f;  // identity (the "+ cnn" term)
#pragma unroll
  for (int i = 0; i < 49; i++) wc[c * 49 + i] = w[i];
  bc[c] = b7[c] + b5[c] + b3[c];
}

// ---------------------------------------------------------------------------
// Depthwise 7x7 conv (cross-correlation, zero pad 3), CHW layout.
// grid (4 xtiles, 16 ytiles, 1024 c), block 256. Tile 64x16 outputs.
__global__ __launch_bounds__(256) void k_dwconv7(const float* __restrict__ X,
    const float* __restrict__ wc, const float* __restrict__ bc,
    float* __restrict__ out) {
  __shared__ float tile[22][72];
  __shared__ float w[49];
  const int c = blockIdx.z;
  const int x0 = blockIdx.x << 6, y0 = blockIdx.y << 4;
  const int tid = threadIdx.x;
  if (tid < 49) w[tid] = wc[c * 49 + tid];
  const float* Xc = X + (size_t)c * HW;
  for (int idx = tid; idx < 22 * 70; idx += 256) {
    const int r = idx / 70, cc = idx % 70;
    const int y = y0 - 3 + r, x = x0 - 3 + cc;
    float vv = 0.f;
    if (y >= 0 && y < SIDE && x >= 0 && x < SIDE) vv = Xc[y * SIDE + x];
    tile[r][cc] = vv;
  }
  __syncthreads();
  const int tx = tid & 15, ty = tid >> 4;
  const int lx = tx << 2;
  float a0 = 0.f, a1 = 0.f, a2 = 0.f, a3 = 0.f;
#pragma unroll
  for (int dy = 0; dy < 7; dy++) {
    float r[10];
#pragma unroll
    for (int i = 0; i < 10; i++) r[i] = tile[ty + dy][lx + i];
#pragma unroll
    for (int dx = 0; dx < 7; dx++) {
      const float ww = w[dy * 7 + dx];
      a0 += ww * r[dx]; a1 += ww * r[dx + 1]; a2 += ww * r[dx + 2]; a3 += ww * r[dx + 3];
    }
  }
  const float b = bc[c];
  float4 o = {a0 + b, a1 + b, a2 + b, a3 + b};
  *(float4*)&out[(size_t)c * HW + (y0 + ty) * SIDE + x0 + lx] = o;
}

// ---------------------------------------------------------------------------
// fp32 GEMM: C[M][N] = op(A[M][K] x B[K][N] + bias[M]); tile 64x64, BK=16,
// 256 threads, 4x4 microtile. grid (M/64, N/64).
template <int RELU>
__global__ __launch_bounds__(256) void k_gemm(const float* __restrict__ A,
    const float* __restrict__ B, const float* __restrict__ bias,
    float* __restrict__ C, int M, int N, int K) {
  __shared__ float As[16][68];
  __shared__ float Bs[16][68];
  const int bm = blockIdx.x << 6, bn = blockIdx.y << 6;
  const int tid = threadIdx.x;
  const int tn = tid & 15, tm = tid >> 4;
  const int la_m = tid >> 2, la_k = (tid & 3) << 2;
  const int lb_k = tid >> 4, lb_n = (tid & 15) << 2;
  const float* Ap = A + (size_t)(bm + la_m) * K + la_k;
  const float* Bp = B + (size_t)lb_k * N + bn + lb_n;
  float acc[4][4] = {};
  for (int k0 = 0; k0 < K; k0 += 16) {
    const float4 a = *(const float4*)(Ap + k0);
    const float4 b = *(const float4*)(Bp + (size_t)k0 * N);
    As[la_k + 0][la_m] = a.x; As[la_k + 1][la_m] = a.y;
    As[la_k + 2][la_m] = a.z; As[la_k + 3][la_m] = a.w;
    *(float4*)&Bs[lb_k][lb_n] = b;
    __syncthreads();
#pragma unroll
    for (int kk = 0; kk < 16; kk++) {
      const float4 av = *(const float4*)&As[kk][tm << 2];
      const float4 bv = *(const float4*)&Bs[kk][tn << 2];
      acc[0][0] += av.x * bv.x; acc[0][1] += av.x * bv.y; acc[0][2] += av.x * bv.z; acc[0][3] += av.x * bv.w;
      acc[1][0] += av.y * bv.x; acc[1][1] += av.y * bv.y; acc[1][2] += av.y * bv.z; acc[1][3] += av.y * bv.w;
      acc[2][0] += av.z * bv.x; acc[2][1] += av.z * bv.y; acc[2][2] += av.z * bv.z; acc[2][3] += av.z * bv.w;
      acc[3][0] += av.w * bv.x; acc[3][1] += av.w * bv.y; acc[3][2] += av.w * bv.z; acc[3][3] += av.w * bv.w;
    }
    __syncthreads();
  }
#pragma unroll
  for (int i = 0; i < 4; i++) {
    const int m = bm + (tm << 2) + i;
    const float bsv = bias[m];
    float4 o;
    o.x = acc[i][0] + bsv; o.y = acc[i][1] + bsv; o.z = acc[i][2] + bsv; o.w = acc[i][3] + bsv;
    if (RELU) {
      o.x = fmaxf(o.x, 0.f); o.y = fmaxf(o.y, 0.f); o.z = fmaxf(o.z, 0.f); o.w = fmaxf(o.w, 0.f);
    }
    *(float4*)&C[(size_t)m * N + bn + (tn << 2)] = o;
  }
}

// ---------------------------------------------------------------------------
// Per-channel 256x256 spatial transpose: out[c][j][i] = in[c][i][j].
// grid (8, 8, C), block (32, 8)
__global__ __launch_bounds__(256) void k_t2d(const float* __restrict__ in,
                                             float* __restrict__ out) {
  __shared__ float t[32][33];
  const size_t base = (size_t)blockIdx.z * HW;
  const int i0 = blockIdx.y << 5, j0 = blockIdx.x << 5;
  const int tx = threadIdx.x, ty = threadIdx.y;
#pragma unroll
  for (int r = 0; r < 32; r += 8)
    t[ty + r][tx] = in[base + (i0 + ty + r) * SIDE + j0 + tx];
  __syncthreads();
#pragma unroll
  for (int r = 0; r < 32; r += 8)
    out[base + (j0 + ty + r) * SIDE + i0 + tx] = t[tx][ty + r];
}

// ---------------------------------------------------------------------------
// Row energy: for each row h: E[h*HW + w*256 + v] = sum_c Q[c][h][w]*K[c][h][v]
// K(dim)=64 channels. grid (4 wtiles, 4 vtiles, 256 rows), block 256.
__global__ __launch_bounds__(256) void k_energy(const float* __restrict__ Q,
    const float* __restrict__ Km, float* __restrict__ E) {
  __shared__ float Qs[16][68], Ks[16][68];
  const int h = blockIdx.z;
  const int w0 = blockIdx.x << 6, v0 = blockIdx.y << 6;
  const int tid = threadIdx.x;
  const int tv = tid & 15, tw = tid >> 4;
  const int lc = tid >> 4, lxx = (tid & 15) << 2;
  const float* Qp = Q + (size_t)lc * HW + h * SIDE + w0 + lxx;
  const float* Kp = Km + (size_t)lc * HW + h * SIDE + v0 + lxx;
  float acc[4][4] = {};
  for (int c0 = 0; c0 < 64; c0 += 16) {
    *(float4*)&Qs[lc][lxx] = *(const float4*)(Qp + (size_t)c0 * HW);
    *(float4*)&Ks[lc][lxx] = *(const float4*)(Kp + (size_t)c0 * HW);
    __syncthreads();
#pragma unroll
    for (int cc = 0; cc < 16; cc++) {
      const float4 qv = *(const float4*)&Qs[cc][tw << 2];
      const float4 kv = *(const float4*)&Ks[cc][tv << 2];
      acc[0][0] += qv.x * kv.x; acc[0][1] += qv.x * kv.y; acc[0][2] += qv.x * kv.z; acc[0][3] += qv.x * kv.w;
      acc[1][0] += qv.y * kv.x; acc[1][1] += qv.y * kv.y; acc[1][2] += qv.y * kv.z; acc[1][3] += qv.y * kv.w;
      acc[2][0] += qv.z * kv.x; acc[2][1] += qv.z * kv.y; acc[2][2] += qv.z * kv.z; acc[2][3] += qv.z * kv.w;
      acc[3][0] += qv.w * kv.x; acc[3][1] += qv.w * kv.y; acc[3][2] += qv.w * kv.z; acc[3][3] += qv.w * kv.w;
    }
    __syncthreads();
  }
#pragma unroll
  for (int i = 0; i < 4; i++) {
    float4 o = {acc[i][0], acc[i][1], acc[i][2], acc[i][3]};
    *(float4*)&E[(size_t)h * HW + (size_t)(w0 + (tw << 2) + i) * SIDE + v0 + (tv << 2)] = o;
  }
}

// ---------------------------------------------------------------------------
// Softmax over 256 entries at stride hStride: for block b, thread j the column
// is E[b*outerStride + j + h*hStride], h=0..255.  grid 256, block 256.
__global__ __launch_bounds__(256) void k_softmax(float* __restrict__ E,
                                                 int outerStride, int hStride) {
  const size_t base = (size_t)blockIdx.x * outerStride + threadIdx.x;
  float m = -3.4e38f;
  for (int h = 0; h < 256; h++) m = fmaxf(m, E[base + (size_t)h * hStride]);
  float s = 0.f;
  for (int h = 0; h < 256; h++) s += expf(E[base + (size_t)h * hStride] - m);
  const float inv = 1.0f / s;
  for (int h = 0; h < 256; h++) {
    const size_t i = base + (size_t)h * hStride;
    E[i] = expf(E[i] - m) * inv;
  }
}

// ---------------------------------------------------------------------------
// Row map: for each row h: O[c][h][w] = sum_v V[c][h][v] * Att[h*HW + w*256 + v]
// grid (4 wtiles, 8 ctiles, 256 rows), block 256, 4x4 microtile, K=256.
__global__ __launch_bounds__(256) void k_map(const float* __restrict__ V,
    const float* __restrict__ Att, float* __restrict__ O) {
  __shared__ float Vs[16][68], Ws[16][68];
  const int h = blockIdx.z;
  const int w0 = blockIdx.x << 6, c0 = blockIdx.y << 6;
  const int tid = threadIdx.x;
  const int tw = tid & 15, tc = tid >> 4;
  const int lr = tid >> 2, lv = (tid & 3) << 2;
  const float* Vp = V + (size_t)(c0 + lr) * HW + h * SIDE + lv;
  const float* Ap = Att + (size_t)h * HW + (size_t)(w0 + lr) * SIDE + lv;
  float acc[4][4] = {};
  for (int kv0 = 0; kv0 < 256; kv0 += 16) {
    const float4 a = *(const float4*)(Vp + kv0);
    const float4 b = *(const float4*)(Ap + kv0);
    Vs[lv + 0][lr] = a.x; Vs[lv + 1][lr] = a.y; Vs[lv + 2][lr] = a.z; Vs[lv + 3][lr] = a.w;
    Ws[lv + 0][lr] = b.x; Ws[lv + 1][lr] = b.y; Ws[lv + 2][lr] = b.z; Ws[lv + 3][lr] = b.w;
    __syncthreads();
#pragma unroll
    for (int vv = 0; vv < 16; vv++) {
      const float4 cv = *(const float4*)&Vs[vv][tc << 2];
      const float4 wv = *(const float4*)&Ws[vv][tw << 2];
      acc[0][0] += cv.x * wv.x; acc[0][1] += cv.x * wv.y; acc[0][2] += cv.x * wv.z; acc[0][3] += cv.x * wv.w;
      acc[1][0] += cv.y * wv.x; acc[1][1] += cv.y * wv.y; acc[1][2] += cv.y * wv.z; acc[1][3] += cv.y * wv.w;
      acc[2][0] += cv.z * wv.x; acc[2][1] += cv.z * wv.y; acc[2][2] += cv.z * wv.z; acc[2][3] += cv.z * wv.w;
      acc[3][0] += cv.w * wv.x; acc[3][1] += cv.w * wv.y; acc[3][2] += cv.w * wv.z; acc[3][3] += cv.w * wv.w;
    }
    __syncthreads();
  }
#pragma unroll
  for (int i = 0; i < 4; i++) {
    float4 o = {acc[i][0], acc[i][1], acc[i][2], acc[i][3]};
    *(float4*)&O[(size_t)(c0 + (tc << 2) + i) * HW + h * SIDE + w0 + (tw << 2)] = o;
  }
}

// ---------------------------------------------------------------------------
// Merge: O[c][h][w] = gamma*(O[c][h][w] + TH[c][w][h]) + cnn[c][h][w]
// grid (8 wtiles, 8 htiles, 512 c), block (32, 8). LDS transpose of TH tile.
__global__ __launch_bounds__(256) void k_merge(float* __restrict__ O,
    const float* __restrict__ TH, const float* __restrict__ CN,
    const float* __restrict__ gammap) {
  __shared__ float t[32][33];
  const float g = *gammap;
  const size_t base = (size_t)blockIdx.z * HW;
  const int h0 = blockIdx.y << 5, w0 = blockIdx.x << 5;
  const int tx = threadIdx.x, ty = threadIdx.y;
#pragma unroll
  for (int r = 0; r < 32; r += 8)
    t[ty + r][tx] = TH[base + (w0 + ty + r) * SIDE + h0 + tx];
  __syncthreads();
#pragma unroll
  for (int r = 0; r < 32; r += 8) {
    const size_t idx = base + (h0 + ty + r) * SIDE + w0 + tx;
    O[idx] = g * (O[idx] + t[tx][ty + r]) + CN[idx];
  }
}

// ---------------------------------------------------------------------------
// logits[n] = sum_j X[j][n]*Wfc[j] + bfc
__global__ __launch_bounds__(256) void k_logits(const float* __restrict__ X,
    const float* __restrict__ Wfc, const float* __restrict__ bfc,
    float* __restrict__ L) {
  const int n = blockIdx.x * 256 + threadIdx.x;
  float s = 0.f;
  for (int j = 0; j < 512; j++) s += X[(size_t)j * HW + n] * Wfc[j];
  L[n] = s + bfc[0];
}

__global__ __launch_bounds__(256) void k_smax_reduce(const float* __restrict__ L,
                                                     float* __restrict__ red) {
  __shared__ float sm[256];
  const int tid = threadIdx.x;
  float m = -3.4e38f;
  for (int i = tid; i < HW; i += 256) m = fmaxf(m, L[i]);
  sm[tid] = m;
  __syncthreads();
  for (int s = 128; s > 0; s >>= 1) {
    if (tid < s) sm[tid] = fmaxf(sm[tid], sm[tid + s]);
    __syncthreads();
  }
  const float M = sm[0];
  __syncthreads();
  float sum = 0.f;
  for (int i = tid; i < HW; i += 256) sum += expf(L[i] - M);
  sm[tid] = sum;
  __syncthreads();
  for (int s = 128; s > 0; s >>= 1) {
    if (tid < s) sm[tid] += sm[tid + s];
    __syncthreads();
  }
  if (tid == 0) { red[0] = M; red[1] = sm[0]; }
}

__global__ __launch_bounds__(256) void k_smax_write(const float* __restrict__ L,
    const float* __restrict__ red, float* __restrict__ out) {
  const int n = blockIdx.x * 256 + threadIdx.x;
  out[n] = expf(L[n] - red[0]) * (1.0f / red[1]);
}

// ---------------------------------------------------------------------------
extern "C" void kernel_launch(void* const* d_in, const int* in_sizes, int n_in,
                              void* d_out, int out_size, void* d_ws, size_t ws_size,
                              hipStream_t stream) {
  const float* h0 = (const float*)d_in[0];
  const float* w7 = (const float*)d_in[1];
  const float* b7 = (const float*)d_in[2];
  const float* w5 = (const float*)d_in[3];
  const float* b5 = (const float*)d_in[4];
  const float* w3 = (const float*)d_in[5];
  const float* b3 = (const float*)d_in[6];
  const float* W1 = (const float*)d_in[7];
  const float* b1 = (const float*)d_in[8];
  const float* Wq = (const float*)d_in[9];
  const float* bq = (const float*)d_in[10];
  const float* Wk = (const float*)d_in[11];
  const float* bk = (const float*)d_in[12];
  const float* Wv = (const float*)d_in[13];
  const float* bv = (const float*)d_in[14];
  const float* gamma = (const float*)d_in[15];
  const float* Wq1 = (const float*)d_in[16];
  const float* bq1 = (const float*)d_in[17];
  const float* Wk1 = (const float*)d_in[18];
  const float* bk1 = (const float*)d_in[19];
  const float* Wv1 = (const float*)d_in[20];
  const float* bv1 = (const float*)d_in[21];
  const float* gamma1 = (const float*)d_in[22];
  const float* Wfc = (const float*)d_in[23];
  const float* bfc = (const float*)d_in[24];

  float* ws = (float*)d_ws;
  const size_t M1 = (size_t)1024 * HW;  // 67,108,864 floats
  const size_t M2 = (size_t)512 * HW;   // 33,554,432
  const size_t MQ = (size_t)64 * HW;    // 4,194,304
  const size_t ME = (size_t)256 * HW;   // 16,777,216

  float* X    = ws;               // [0,      M1)
  float* H1   = ws + M1;          // [M1,   2*M1)
  float* H2   = ws;               // reuse X region after conv
  float* q    = ws + M2;          // within old X region
  float* kq   = q + MQ;
  float* qT   = kq + MQ;
  float* kT   = qT + MQ;
  float* TH   = ws + M2;          // reuses q..kT after energies are done
  float* v    = ws + M1;          // reuse H1 region after fc1
  float* vT   = v + M2;
  float* E    = ws + 2 * M1;      // [2*M1, 2*M1+ME)
  float* OUT1 = E + ME;           // [.., +M2)
  float* OUT2 = ws;               // reuses H2 region in block 2
  float* wcomb = OUT1 + M2;
  float* bcomb = wcomb + 1024 * 49;
  float* L    = bcomb + 1024;
  float* red  = L + HW;

  // --- PPEG ---
  k_transpose_nc<<<dim3(2048, 32), dim3(32, 8), 0, stream>>>(h0, X);
  k_wcomb<<<4, 256, 0, stream>>>(w7, b7, w5, b5, w3, b3, wcomb, bcomb);
  k_dwconv7<<<dim3(4, 16, 1024), 256, 0, stream>>>(X, wcomb, bcomb, H1);

  // --- fc1 + ReLU, output in CHW layout: H2[j][n] ---
  k_gemm<1><<<dim3(8, 1024), 256, 0, stream>>>(W1, H1, b1, H2, 512, HW, 1024);

  auto cc_block = [&](const float* cnn, float* out, const float* Wq_,
                      const float* bq_, const float* Wk_, const float* bk_,
                      const float* Wv_, const float* bv_, const float* gam) {
    k_gemm<0><<<dim3(1, 1024), 256, 0, stream>>>(Wq_, cnn, bq_, q, 64, HW, 512);
    k_gemm<0><<<dim3(1, 1024), 256, 0, stream>>>(Wk_, cnn, bk_, kq, 64, HW, 512);
    k_gemm<0><<<dim3(8, 1024), 256, 0, stream>>>(Wv_, cnn, bv_, v, 512, HW, 512);
    k_t2d<<<dim3(8, 8, 64), dim3(32, 8), 0, stream>>>(q, qT);
    k_t2d<<<dim3(8, 8, 64), dim3(32, 8), 0, stream>>>(kq, kT);
    k_t2d<<<dim3(8, 8, 512), dim3(32, 8), 0, stream>>>(v, vT);
    // W path (rows): EW[h][w][v], softmax over h (stride HW), map -> out
    k_energy<<<dim3(4, 4, 256), 256, 0, stream>>>(q, kq, E);
    k_softmax<<<256, 256, 0, stream>>>(E, 256, HW);
    k_map<<<dim3(4, 8, 256), 256, 0, stream>>>(v, E, out);
    // H path (columns = rows of transposed image): EH'[w][h][g], softmax over
    // h (stride 256), map -> TH[c][w][h]
    k_energy<<<dim3(4, 4, 256), 256, 0, stream>>>(qT, kT, E);
    k_softmax<<<256, 256, 0, stream>>>(E, HW, 256);
    k_map<<<dim3(4, 8, 256), 256, 0, stream>>>(vT, E, TH);
    // out = gamma*(out + TH^T) + cnn
    k_merge<<<dim3(8, 8, 512), dim3(32, 8), 0, stream>>>(out, TH, cnn, gam);
  };

  cc_block(H2, OUT1, Wq, bq, Wk, bk, Wv, bv, gamma);
  cc_block(OUT1, OUT2, Wq1, bq1, Wk1, bk1, Wv1, bv1, gamma1);

  // --- final fc + instance softmax ---
  k_logits<<<256, 256, 0, stream>>>(OUT2, Wfc, bfc, L);
  k_smax_reduce<<<1, 256, 0, stream>>>(L, red);
  k_smax_write<<<256, 256, 0, stream>>>(L, red, (float*)d_out);
}

// Round 2
// 1772.820 us; speedup vs baseline: 2.8173x; 2.8173x over previous
//
#include <hip/hip_runtime.h>

#define HW 65536
#define SIDE 256

typedef __attribute__((ext_vector_type(8))) short short8v;
typedef __attribute__((ext_vector_type(4))) float f32x4;

__device__ __forceinline__ ushort f2bf(float f) {
  unsigned int u = __builtin_bit_cast(unsigned int, f);
  u = (u + 0x7fff + ((u >> 16) & 1)) >> 16;
  return (ushort)u;
}

// ---------------------------------------------------------------------------
// Transpose h0 [N=65536][C=1024] -> X [C][N] fp32
__global__ __launch_bounds__(256) void k_transpose_nc(const float* __restrict__ in,
                                                      float* __restrict__ out) {
  __shared__ float t[32][33];
  const int n0 = blockIdx.x << 5, c0 = blockIdx.y << 5;
  const int tx = threadIdx.x, ty = threadIdx.y;
#pragma unroll
  for (int r = 0; r < 32; r += 8)
    t[ty + r][tx] = in[(size_t)(n0 + ty + r) * 1024 + c0 + tx];
  __syncthreads();
#pragma unroll
  for (int r = 0; r < 32; r += 8)
    out[(size_t)(c0 + ty + r) * HW + n0 + tx] = t[tx][ty + r];
}

// ---------------------------------------------------------------------------
__global__ __launch_bounds__(256) void k_wcomb(const float* __restrict__ w7,
    const float* __restrict__ b7, const float* __restrict__ w5,
    const float* __restrict__ b5, const float* __restrict__ w3,
    const float* __restrict__ b3, float* __restrict__ wc, float* __restrict__ bc) {
  const int c = blockIdx.x * 256 + threadIdx.x;
  if (c >= 1024) return;
  float w[49];
#pragma unroll
  for (int i = 0; i < 49; i++) w[i] = w7[c * 49 + i];
  for (int dy = 0; dy < 5; dy++)
    for (int dx = 0; dx < 5; dx++)
      w[(dy + 1) * 7 + (dx + 1)] += w5[c * 25 + dy * 5 + dx];
  for (int dy = 0; dy < 3; dy++)
    for (int dx = 0; dx < 3; dx++)
      w[(dy + 2) * 7 + (dx + 2)] += w3[c * 9 + dy * 3 + dx];
  w[3 * 7 + 3] += 1.0f;
#pragma unroll
  for (int i = 0; i < 49; i++) wc[c * 49 + i] = w[i];
  bc[c] = b7[c] + b5[c] + b3[c];
}

// ---------------------------------------------------------------------------
// Depthwise 7x7 conv, CHW, fp32 compute, bf16 output.
__global__ __launch_bounds__(256) void k_dwconv7(const float* __restrict__ X,
    const float* __restrict__ wc, const float* __restrict__ bc,
    ushort* __restrict__ out) {
  __shared__ float tile[22][72];
  __shared__ float w[49];
  const int c = blockIdx.z;
  const int x0 = blockIdx.x << 6, y0 = blockIdx.y << 4;
  const int tid = threadIdx.x;
  if (tid < 49) w[tid] = wc[c * 49 + tid];
  const float* Xc = X + (size_t)c * HW;
  for (int idx = tid; idx < 22 * 70; idx += 256) {
    const int r = idx / 70, cc = idx % 70;
    const int y = y0 - 3 + r, x = x0 - 3 + cc;
    float vv = 0.f;
    if (y >= 0 && y < SIDE && x >= 0 && x < SIDE) vv = Xc[y * SIDE + x];
    tile[r][cc] = vv;
  }
  __syncthreads();
  const int tx = tid & 15, ty = tid >> 4;
  const int lx = tx << 2;
  float a0 = 0.f, a1 = 0.f, a2 = 0.f, a3 = 0.f;
#pragma unroll
  for (int dy = 0; dy < 7; dy++) {
    float r[10];
#pragma unroll
    for (int i = 0; i < 10; i++) r[i] = tile[ty + dy][lx + i];
#pragma unroll
    for (int dx = 0; dx < 7; dx++) {
      const float ww = w[dy * 7 + dx];
      a0 += ww * r[dx]; a1 += ww * r[dx + 1]; a2 += ww * r[dx + 2]; a3 += ww * r[dx + 3];
    }
  }
  const float b = bc[c];
  ushort4 o = {f2bf(a0 + b), f2bf(a1 + b), f2bf(a2 + b), f2bf(a3 + b)};
  *(ushort4*)&out[(size_t)c * HW + (y0 + ty) * SIDE + x0 + lx] = o;
}

// ---------------------------------------------------------------------------
// Generic batched ushort (bf16) transpose: in [R][C] -> out [C][R].
// grid (C/64, R/64, batch), block 256.
__global__ __launch_bounds__(256) void k_tr_u16(const ushort* __restrict__ in,
    ushort* __restrict__ out, int R, int C, long long bs) {
  __shared__ ushort t[64][66];
  const size_t base = (size_t)blockIdx.z * bs;
  const int c0 = blockIdx.x << 6, r0 = blockIdx.y << 6;
  const int tx = threadIdx.x & 63, ty = threadIdx.x >> 6;
#pragma unroll
  for (int i = 0; i < 64; i += 4)
    t[ty + i][tx] = in[base + (size_t)(r0 + ty + i) * C + c0 + tx];
  __syncthreads();
#pragma unroll
  for (int i = 0; i < 64; i += 4)
    out[base + (size_t)(c0 + ty + i) * R + r0 + tx] = t[tx][ty + i];
}

// ---------------------------------------------------------------------------
// bf16 MFMA GEMM:  C[m][n] = sum_k A[m][k] * B[n][k]  (both K-contiguous)
// Tiles 128(M) x BN(N), BK=32, 4 waves (2x2), 4xFN frags of 16x16x32.
// BIAS: 0 none, 1 bias[row], 2 bias[col].  OUTF/OUTB: write fp32 / bf16.
template <int BN, int BIAS, int RELU, int OUTF, int OUTB>
__global__ __launch_bounds__(256) void k_mm(
    const ushort* __restrict__ A, int lda, long long bsA,
    const ushort* __restrict__ B, int ldb, long long bsB,
    const float* __restrict__ bias,
    float* __restrict__ Cf, ushort* __restrict__ Cb, int ldc, long long bsC,
    int K) {
  static_assert(BN == 64 || BN == 128, "BN");
  constexpr int FN = BN / 32;
  __shared__ __align__(16) ushort As[128 * 32];
  __shared__ __align__(16) ushort Bs[BN * 32];
  const int tid = threadIdx.x;
  const int bm = blockIdx.x << 7, bn = blockIdx.y * BN;
  const long long zA = (long long)blockIdx.z * bsA;
  const long long zB = (long long)blockIdx.z * bsB;
  const long long zC = (long long)blockIdx.z * bsC;

  // staging: thread -> (row, lds-chunk); global chunk = lds-chunk ^ swz(row)
  const int sr = tid >> 2, sq = tid & 3;
  const int sw0 = (sr >> 1) & 3;
  const int sw1 = ((sr + 64) >> 1) & 3;
  const ushort* Ap0 = A + zA + (size_t)(bm + sr) * lda + ((sq ^ sw0) << 3);
  const ushort* Ap1 = A + zA + (size_t)(bm + sr + 64) * lda + ((sq ^ sw1) << 3);
  const ushort* Bp0 = B + zB + (size_t)(bn + sr) * ldb + ((sq ^ sw0) << 3);
  const ushort* Bp1 = nullptr;
  if constexpr (BN == 128)
    Bp1 = B + zB + (size_t)(bn + sr + 64) * ldb + ((sq ^ sw1) << 3);
  ushort* wA0 = &As[sr * 32 + sq * 8];
  ushort* wA1 = &As[(sr + 64) * 32 + sq * 8];
  ushort* wB0 = &Bs[sr * 32 + sq * 8];
  ushort* wB1 = nullptr;
  if constexpr (BN == 128) wB1 = &Bs[(sr + 64) * 32 + sq * 8];

  // fragment coords
  const int lane = tid & 63, wv = tid >> 6;
  const int wm = wv & 1, wn = wv >> 1;
  const int fr = lane & 15, kq = lane >> 4;
  int offA[4], offB[FN];
#pragma unroll
  for (int mi = 0; mi < 4; mi++) {
    const int row = wm * 64 + mi * 16 + fr;
    offA[mi] = row * 32 + ((kq ^ ((row >> 1) & 3)) << 3);
  }
#pragma unroll
  for (int ni = 0; ni < FN; ni++) {
    const int row = wn * (BN / 2) + ni * 16 + fr;
    offB[ni] = row * 32 + ((kq ^ ((row >> 1) & 3)) << 3);
  }

  f32x4 acc[4][FN];
#pragma unroll
  for (int mi = 0; mi < 4; mi++)
#pragma unroll
    for (int ni = 0; ni < FN; ni++) acc[mi][ni] = (f32x4){0.f, 0.f, 0.f, 0.f};

  for (int k0 = 0; k0 < K; k0 += 32) {
    const uint4 ga0 = *(const uint4*)(Ap0 + k0);
    const uint4 ga1 = *(const uint4*)(Ap1 + k0);
    const uint4 gb0 = *(const uint4*)(Bp0 + k0);
    uint4 gb1;
    if constexpr (BN == 128) gb1 = *(const uint4*)(Bp1 + k0);
    __syncthreads();
    *(uint4*)wA0 = ga0;
    *(uint4*)wA1 = ga1;
    *(uint4*)wB0 = gb0;
    if constexpr (BN == 128) *(uint4*)wB1 = gb1;
    __syncthreads();
    short8v a[4], b[FN];
#pragma unroll
    for (int mi = 0; mi < 4; mi++) a[mi] = *(const short8v*)&As[offA[mi]];
#pragma unroll
    for (int ni = 0; ni < FN; ni++) b[ni] = *(const short8v*)&Bs[offB[ni]];
#pragma unroll
    for (int mi = 0; mi < 4; mi++)
#pragma unroll
      for (int ni = 0; ni < FN; ni++)
        acc[mi][ni] = __builtin_amdgcn_mfma_f32_16x16x32_bf16(a[mi], b[ni], acc[mi][ni], 0, 0, 0);
  }

#pragma unroll
  for (int mi = 0; mi < 4; mi++) {
#pragma unroll
    for (int ni = 0; ni < FN; ni++) {
#pragma unroll
      for (int r = 0; r < 4; r++) {
        const int row = bm + wm * 64 + mi * 16 + (lane >> 4) * 4 + r;
        const int col = bn + wn * (BN / 2) + ni * 16 + fr;
        float v = acc[mi][ni][r];
        if (BIAS == 1) v += bias[row];
        if (BIAS == 2) v += bias[col];
        if (RELU) v = fmaxf(v, 0.f);
        const size_t idx = (size_t)(zC + (size_t)row * ldc + col);
        if (OUTF) Cf[idx] = v;
        if (OUTB) Cb[idx] = f2bf(v);
      }
    }
  }
}

// ---------------------------------------------------------------------------
// Online softmax over 256 entries at stride hStride, fp32 in -> bf16 out.
__global__ __launch_bounds__(256) void k_softmax_bf16(const float* __restrict__ E,
    ushort* __restrict__ Att, int outerStride, int hStride) {
  const size_t base = (size_t)blockIdx.x * outerStride + threadIdx.x;
  float m = -3.4e38f, s = 0.f;
  for (int h = 0; h < 256; h++) {
    const float x = E[base + (size_t)h * hStride];
    const float nm = fmaxf(m, x);
    s = s * __expf(m - nm) + __expf(x - nm);
    m = nm;
  }
  const float inv = 1.0f / s;
  for (int h = 0; h < 256; h++) {
    const size_t i = base + (size_t)h * hStride;
    Att[i] = f2bf(__expf(E[i] - m) * inv);
  }
}

// ---------------------------------------------------------------------------
// outF[c][h][w] = gamma*(O[c][h][w] + TH[c][w][h]) + CN[c][h][w]; optional bf16.
__global__ __launch_bounds__(256) void k_merge2(const float* __restrict__ O,
    const float* __restrict__ TH, const float* __restrict__ CN,
    const float* __restrict__ gammap, float* __restrict__ outF,
    ushort* __restrict__ outB) {
  __shared__ float t[32][33];
  const float g = *gammap;
  const size_t base = (size_t)blockIdx.z * HW;
  const int h0 = blockIdx.y << 5, w0 = blockIdx.x << 5;
  const int tx = threadIdx.x, ty = threadIdx.y;
#pragma unroll
  for (int r = 0; r < 32; r += 8)
    t[ty + r][tx] = TH[base + (w0 + ty + r) * SIDE + h0 + tx];
  __syncthreads();
#pragma unroll
  for (int r = 0; r < 32; r += 8) {
    const size_t idx = base + (h0 + ty + r) * SIDE + w0 + tx;
    const float v = g * (O[idx] + t[tx][ty + r]) + CN[idx];
    outF[idx] = v;
    if (outB) outB[idx] = f2bf(v);
  }
}

// ---------------------------------------------------------------------------
__global__ __launch_bounds__(256) void k_logits(const float* __restrict__ X,
    const float* __restrict__ Wfc, const float* __restrict__ bfc,
    float* __restrict__ L) {
  const int n = blockIdx.x * 256 + threadIdx.x;
  float s = 0.f;
  for (int j = 0; j < 512; j++) s += X[(size_t)j * HW + n] * Wfc[j];
  L[n] = s + bfc[0];
}

__global__ __launch_bounds__(256) void k_smax_reduce(const float* __restrict__ L,
                                                     float* __restrict__ red) {
  __shared__ float sm[256];
  const int tid = threadIdx.x;
  float m = -3.4e38f;
  for (int i = tid; i < HW; i += 256) m = fmaxf(m, L[i]);
  sm[tid] = m;
  __syncthreads();
  for (int s = 128; s > 0; s >>= 1) {
    if (tid < s) sm[tid] = fmaxf(sm[tid], sm[tid + s]);
    __syncthreads();
  }
  const float M = sm[0];
  __syncthreads();
  float sum = 0.f;
  for (int i = tid; i < HW; i += 256) sum += expf(L[i] - M);
  sm[tid] = sum;
  __syncthreads();
  for (int s = 128; s > 0; s >>= 1) {
    if (tid < s) sm[tid] += sm[tid + s];
    __syncthreads();
  }
  if (tid == 0) { red[0] = M; red[1] = sm[0]; }
}

__global__ __launch_bounds__(256) void k_smax_write(const float* __restrict__ L,
    const float* __restrict__ red, float* __restrict__ out) {
  const int n = blockIdx.x * 256 + threadIdx.x;
  out[n] = expf(L[n] - red[0]) * (1.0f / red[1]);
}

__global__ void k_f2b(const float* __restrict__ in, ushort* __restrict__ out, int n) {
  const int i = blockIdx.x * 256 + threadIdx.x;
  if (i < n) out[i] = f2bf(in[i]);
}

__global__ void k_cpy(const float* __restrict__ a, float* __restrict__ b, int n) {
  const int i = blockIdx.x * 256 + threadIdx.x;
  if (i < n) b[i] = a[i];
}

// ---------------------------------------------------------------------------
extern "C" void kernel_launch(void* const* d_in, const int* in_sizes, int n_in,
                              void* d_out, int out_size, void* d_ws, size_t ws_size,
                              hipStream_t stream) {
  const float* h0 = (const float*)d_in[0];
  const float* w7 = (const float*)d_in[1];
  const float* b7 = (const float*)d_in[2];
  const float* w5 = (const float*)d_in[3];
  const float* b5 = (const float*)d_in[4];
  const float* w3 = (const float*)d_in[5];
  const float* b3 = (const float*)d_in[6];
  const float* W1 = (const float*)d_in[7];
  const float* b1 = (const float*)d_in[8];
  const float* Wq = (const float*)d_in[9];
  const float* bq = (const float*)d_in[10];
  const float* Wk = (const float*)d_in[11];
  const float* bk = (const float*)d_in[12];
  const float* Wv = (const float*)d_in[13];
  const float* bv = (const float*)d_in[14];
  const float* gamma = (const float*)d_in[15];
  const float* Wq1 = (const float*)d_in[16];
  const float* bq1 = (const float*)d_in[17];
  const float* Wk1 = (const float*)d_in[18];
  const float* bk1 = (const float*)d_in[19];
  const float* Wv1 = (const float*)d_in[20];
  const float* bv1 = (const float*)d_in[21];
  const float* gamma1 = (const float*)d_in[22];
  const float* Wfc = (const float*)d_in[23];
  const float* bfc = (const float*)d_in[24];

  char* W = (char*)d_ws;
  const size_t MB = 1 << 20;
  // Phase-disjoint workspace plan (max ~708 MB; previous round used 739 MB OK):
  float*  X     = (float*)(W + 0);           // [0,256) fp32, dead after conv
  ushort* H2b   = (ushort*)(W + 0);          // [0,64) bf16
  ushort* H2t   = (ushort*)(W + 64 * MB);    // [64,128) bf16; later out1t
  ushort* qkt   = (ushort*)(W + 128 * MB);   // [128,144) bf16 [n][128]
  ushort* AttW  = (ushort*)(W + 144 * MB);   // [144,176)
  ushort* AttH  = (ushort*)(W + 176 * MB);   // [176,208)
  ushort* out1b = (ushort*)(W + 144 * MB);   // [144,208) transient (merge1)
  float*  THb   = (float*)(W + 0);           // [0,128) fp32 (after H2b/H2t dead)
  ushort* H1b   = (ushort*)(W + 256 * MB);   // [256,384) bf16
  float*  H2f   = (float*)(W + 256 * MB);    // [256,384) fp32; out1f/OUT2 in-place
  ushort* H1t   = (ushort*)(W + 384 * MB);   // [384,512) bf16
  ushort* Vb    = (ushort*)(W + 384 * MB);   // [384,448) bf16 (after H1t dead)
  ushort* vTb   = (ushort*)(W + 448 * MB);   // [448,512) bf16
  float*  Obuf  = (float*)(W + 512 * MB);    // [512,640) fp32
  float*  Ebuf  = (float*)(W + 640 * MB);    // [640,704) fp32
  ushort* W1b   = (ushort*)(W + 704 * MB);
  ushort* Wvb   = (ushort*)(W + 705 * MB);
  ushort* Wv1b  = (ushort*)(W + 705 * MB + 512 * 1024);
  ushort* Wqkb  = (ushort*)(W + 706 * MB);
  ushort* Wqk1b = (ushort*)(W + 706 * MB + 128 * 1024);
  float*  wcomb = (float*)(W + 706 * MB + 256 * 1024);
  float*  bcomb = (float*)(W + 706 * MB + 464 * 1024);
  float*  bqk   = (float*)(W + 706 * MB + 472 * 1024);
  float*  bqk1  = (float*)(W + 706 * MB + 474 * 1024);
  float*  L     = (float*)(W + 707 * MB);
  float*  red   = (float*)(W + 707 * MB + 256 * 1024);

  // --- weight prep (bf16 casts, q|k concat) ---
  k_f2b<<<2048, 256, 0, stream>>>(W1, W1b, 512 * 1024);
  k_f2b<<<1024, 256, 0, stream>>>(Wv, Wvb, 256 * 1024);
  k_f2b<<<1024, 256, 0, stream>>>(Wv1, Wv1b, 256 * 1024);
  k_f2b<<<128, 256, 0, stream>>>(Wq, Wqkb, 32768);
  k_f2b<<<128, 256, 0, stream>>>(Wk, Wqkb + 32768, 32768);
  k_f2b<<<128, 256, 0, stream>>>(Wq1, Wqk1b, 32768);
  k_f2b<<<128, 256, 0, stream>>>(Wk1, Wqk1b + 32768, 32768);
  k_cpy<<<1, 256, 0, stream>>>(bq, bqk, 64);
  k_cpy<<<1, 256, 0, stream>>>(bk, bqk + 64, 64);
  k_cpy<<<1, 256, 0, stream>>>(bq1, bqk1, 64);
  k_cpy<<<1, 256, 0, stream>>>(bk1, bqk1 + 64, 64);
  k_wcomb<<<4, 256, 0, stream>>>(w7, b7, w5, b5, w3, b3, wcomb, bcomb);

  // --- PPEG ---
  k_transpose_nc<<<dim3(2048, 32), dim3(32, 8), 0, stream>>>(h0, X);
  k_dwconv7<<<dim3(4, 16, 1024), 256, 0, stream>>>(X, wcomb, bcomb, H1b);
  k_tr_u16<<<dim3(1024, 16, 1), 256, 0, stream>>>(H1b, H1t, 1024, HW, 0);

  // --- fc1 + ReLU: H2 = relu(W1 x H1) ; CHW fp32 + bf16 ---
  k_mm<128, 1, 1, 1, 1><<<dim3(4, 512, 1), 256, 0, stream>>>(
      W1b, 1024, 0, H1t, 1024, 0, b1, H2f, H2b, HW, 0, 1024);
  k_tr_u16<<<dim3(1024, 8, 1), 256, 0, stream>>>(H2b, H2t, 512, HW, 0);

  auto cc_block = [&](const ushort* act, float* cnn, const ushort* Wqk_,
                      const float* bqk_, const ushort* Wv_, const float* bv_,
                      const float* gam, ushort* outB16) {
    // fused q|k: qkt[n][128]
    k_mm<128, 2, 0, 0, 1><<<dim3(512, 1, 1), 256, 0, stream>>>(
        act, 512, 0, Wqk_, 512, 0, bqk_, nullptr, qkt, 128, 0, 512);
    // v: CHW bf16
    k_mm<128, 1, 0, 0, 1><<<dim3(4, 512, 1), 256, 0, stream>>>(
        Wv_, 512, 0, act, 512, 0, bv_, nullptr, Vb, HW, 0, 512);
    k_tr_u16<<<dim3(4, 4, 512), 256, 0, stream>>>(Vb, vTb, 256, 256, 65536);
    // W path (rows, batch h): E[h][w][v], softmax over h (stride HW)
    k_mm<128, 0, 0, 1, 0><<<dim3(2, 2, 256), 256, 0, stream>>>(
        qkt, 128, 32768, qkt + 64, 128, 32768, nullptr, Ebuf, nullptr, 256, 65536, 64);
    k_softmax_bf16<<<256, 256, 0, stream>>>(Ebuf, AttW, 256, HW);
    k_mm<128, 0, 0, 1, 0><<<dim3(4, 2, 256), 256, 0, stream>>>(
        Vb, HW, 256, AttW, 256, 65536, nullptr, Obuf, nullptr, HW, 256, 256);
    // H path (columns, batch w): E[w][h][g], softmax over h (stride 256)
    k_mm<128, 0, 0, 1, 0><<<dim3(2, 2, 256), 256, 0, stream>>>(
        qkt, 32768, 128, qkt + 64, 32768, 128, nullptr, Ebuf, nullptr, 256, 65536, 64);
    k_softmax_bf16<<<256, 256, 0, stream>>>(Ebuf, AttH, HW, 256);
    k_mm<128, 0, 0, 1, 0><<<dim3(4, 2, 256), 256, 0, stream>>>(
        vTb, HW, 256, AttH, 256, 65536, nullptr, THb, nullptr, HW, 256, 256);
    // out = gamma*(O + TH^T) + cnn  (fp32 in-place over cnn; optional bf16)
    k_merge2<<<dim3(8, 8, 512), dim3(32, 8), 0, stream>>>(
        Obuf, THb, cnn, gam, cnn, outB16);
  };

  cc_block(H2t, H2f, Wqkb, bqk, Wvb, bv, gamma, out1b);
  // out1 bf16 -> [n][c] layout (reuses H2t region, which is dead)
  k_tr_u16<<<dim3(1024, 8, 1), 256, 0, stream>>>(out1b, H2t, 512, HW, 0);
  cc_block(H2t, H2f, Wqk1b, bqk1, Wv1b, bv1, gamma1, nullptr);

  // --- final fc + instance softmax ---
  k_logits<<<256, 256, 0, stream>>>(H2f, Wfc, bfc, L);
  k_smax_reduce<<<1, 256, 0, stream>>>(L, red);
  k_smax_write<<<256, 256, 0, stream>>>(L, red, (float*)d_out);
}

// Round 4
// 1596.543 us; speedup vs baseline: 3.1284x; 1.1104x over previous
//
#include <hip/hip_runtime.h>

#define HW 65536
#define SIDE 256

typedef __attribute__((ext_vector_type(8))) short short8v;
typedef __attribute__((ext_vector_type(4))) float f32x4;

__device__ __forceinline__ ushort f2bf(float f) {
  unsigned int u = __builtin_bit_cast(unsigned int, f);
  u = (u + 0x7fff + ((u >> 16) & 1)) >> 16;
  return (ushort)u;
}
__device__ __forceinline__ float bf2f(ushort u) {
  return __builtin_bit_cast(float, (unsigned int)u << 16);
}
__device__ __forceinline__ void gld16(const void* g, void* l) {
  __builtin_amdgcn_global_load_lds(
      (const __attribute__((address_space(1))) void*)g,
      (__attribute__((address_space(3))) void*)l, 16, 0, 0);
}

// ---------------------------------------------------------------------------
// Transpose h0 [N=65536][C=1024] fp32 -> X [C][N] bf16
__global__ __launch_bounds__(256) void k_transpose_nc(const float* __restrict__ in,
                                                      ushort* __restrict__ out) {
  __shared__ float t[32][33];
  const int n0 = blockIdx.x << 5, c0 = blockIdx.y << 5;
  const int tx = threadIdx.x, ty = threadIdx.y;
#pragma unroll
  for (int r = 0; r < 32; r += 8)
    t[ty + r][tx] = in[(size_t)(n0 + ty + r) * 1024 + c0 + tx];
  __syncthreads();
#pragma unroll
  for (int r = 0; r < 32; r += 8)
    out[(size_t)(c0 + ty + r) * HW + n0 + tx] = f2bf(t[tx][ty + r]);
}

// ---------------------------------------------------------------------------
__global__ __launch_bounds__(256) void k_wcomb(const float* __restrict__ w7,
    const float* __restrict__ b7, const float* __restrict__ w5,
    const float* __restrict__ b5, const float* __restrict__ w3,
    const float* __restrict__ b3, float* __restrict__ wc, float* __restrict__ bc) {
  const int c = blockIdx.x * 256 + threadIdx.x;
  if (c >= 1024) return;
  float w[49];
#pragma unroll
  for (int i = 0; i < 49; i++) w[i] = w7[c * 49 + i];
  for (int dy = 0; dy < 5; dy++)
    for (int dx = 0; dx < 5; dx++)
      w[(dy + 1) * 7 + (dx + 1)] += w5[c * 25 + dy * 5 + dx];
  for (int dy = 0; dy < 3; dy++)
    for (int dx = 0; dx < 3; dx++)
      w[(dy + 2) * 7 + (dx + 2)] += w3[c * 9 + dy * 3 + dx];
  w[3 * 7 + 3] += 1.0f;
#pragma unroll
  for (int i = 0; i < 49; i++) wc[c * 49 + i] = w[i];
  bc[c] = b7[c] + b5[c] + b3[c];
}

// ---------------------------------------------------------------------------
// Depthwise 7x7 conv, CHW, bf16 in -> fp32 compute -> bf16 out.
// grid (4, 4, 1024): 64x64 output tile. Thread (tx,ty): cols x0+4tx..+3,
// rows y0+4ty..+3. Tap rows read as 3x ds_read_b128 (conflict-free within
// 16-lane phase groups).
__global__ __launch_bounds__(256) void k_dwconv7(const ushort* __restrict__ X,
    const float* __restrict__ wc, const float* __restrict__ bc,
    ushort* __restrict__ out) {
  __shared__ float tile[70][72];
  __shared__ float w[49];
  const int c = blockIdx.z;
  const int x0 = blockIdx.x << 6, y0 = blockIdx.y << 6;
  const int tid = threadIdx.x;
  if (tid < 49) w[tid] = wc[c * 49 + tid];
  const ushort* Xc = X + (size_t)c * HW;
  for (int idx = tid; idx < 70 * 70; idx += 256) {
    const int r = idx / 70, cc = idx % 70;
    const int y = y0 - 3 + r, x = x0 - 3 + cc;
    float vv = 0.f;
    if (y >= 0 && y < SIDE && x >= 0 && x < SIDE) vv = bf2f(Xc[y * SIDE + x]);
    tile[r][cc] = vv;
  }
  __syncthreads();
  const int tx = tid & 15, ty = tid >> 4;
  const int lx = tx << 2;
  float acc[4][4] = {};
#pragma unroll
  for (int q = 0; q < 10; q++) {
    const int r = (ty << 2) + q;
    float rv[12];
    *(float4*)&rv[0] = *(const float4*)&tile[r][lx];
    *(float4*)&rv[4] = *(const float4*)&tile[r][lx + 4];
    *(float4*)&rv[8] = *(const float4*)&tile[r][lx + 8];
#pragma unroll
    for (int m = 0; m < 4; m++) {
      const int dy = q - m;
      if (dy < 0 || dy > 6) continue;
#pragma unroll
      for (int dx = 0; dx < 7; dx++) {
        const float ww = w[dy * 7 + dx];
#pragma unroll
        for (int o = 0; o < 4; o++) acc[m][o] += ww * rv[o + dx];
      }
    }
  }
  const float b = bc[c];
#pragma unroll
  for (int m = 0; m < 4; m++) {
    ushort4 o4 = {f2bf(acc[m][0] + b), f2bf(acc[m][1] + b),
                  f2bf(acc[m][2] + b), f2bf(acc[m][3] + b)};
    *(ushort4*)&out[(size_t)c * HW + (y0 + (ty << 2) + m) * SIDE + x0 + lx] = o4;
  }
}

// ---------------------------------------------------------------------------
// Generic batched ushort (bf16) transpose: in [R][C] -> out [C][R].
__global__ __launch_bounds__(256) void k_tr_u16(const ushort* __restrict__ in,
    ushort* __restrict__ out, int R, int C, long long bs) {
  __shared__ ushort t[64][66];
  const size_t base = (size_t)blockIdx.z * bs;
  const int c0 = blockIdx.x << 6, r0 = blockIdx.y << 6;
  const int tx = threadIdx.x & 63, ty = threadIdx.x >> 6;
#pragma unroll
  for (int i = 0; i < 64; i += 4)
    t[ty + i][tx] = in[base + (size_t)(r0 + ty + i) * C + c0 + tx];
  __syncthreads();
#pragma unroll
  for (int i = 0; i < 64; i += 4)
    out[base + (size_t)(c0 + ty + i) * R + r0 + tx] = t[tx][ty + i];
}

// ---------------------------------------------------------------------------
// bf16 MFMA GEMM:  C[m][n] = sum_k A[m][k] * B[n][k]  (both K-contiguous)
// 128x128 tile, BK=32, 4 waves, global_load_lds staging (pre-swizzled source,
// linear LDS dest; XOR-swizzled fragment reads).
template <int BN, int BIAS, int RELU, int OUTF, int OUTB>
__global__ __launch_bounds__(256) void k_mm(
    const ushort* __restrict__ A, int lda, long long bsA,
    const ushort* __restrict__ B, int ldb, long long bsB,
    const float* __restrict__ bias,
    float* __restrict__ Cf, ushort* __restrict__ Cb, int ldc, long long bsC,
    int K) {
  static_assert(BN == 64 || BN == 128, "BN");
  constexpr int FN = BN / 32;
  __shared__ __align__(16) ushort As[128 * 32];
  __shared__ __align__(16) ushort Bs[BN * 32];
  const int tid = threadIdx.x;
  const int bm = blockIdx.x << 7, bn = blockIdx.y * BN;
  const long long zA = (long long)blockIdx.z * bsA;
  const long long zB = (long long)blockIdx.z * bsB;
  const long long zC = (long long)blockIdx.z * bsC;

  const int sr = tid >> 2, sq = tid & 3;
  const int sw0 = (sr >> 1) & 3;
  const int sw1 = ((sr + 64) >> 1) & 3;
  const ushort* Ap0 = A + zA + (size_t)(bm + sr) * lda + ((sq ^ sw0) << 3);
  const ushort* Ap1 = A + zA + (size_t)(bm + sr + 64) * lda + ((sq ^ sw1) << 3);
  const ushort* Bp0 = B + zB + (size_t)(bn + sr) * ldb + ((sq ^ sw0) << 3);
  const ushort* Bp1 = nullptr;
  if constexpr (BN == 128)
    Bp1 = B + zB + (size_t)(bn + sr + 64) * ldb + ((sq ^ sw1) << 3);
  ushort* wA0 = &As[sr * 32 + sq * 8];
  ushort* wA1 = &As[(sr + 64) * 32 + sq * 8];
  ushort* wB0 = &Bs[sr * 32 + sq * 8];
  ushort* wB1 = nullptr;
  if constexpr (BN == 128) wB1 = &Bs[(sr + 64) * 32 + sq * 8];

  const int lane = tid & 63, wv = tid >> 6;
  const int wm = wv & 1, wn = wv >> 1;
  const int fr = lane & 15, kq = lane >> 4;
  int offA[4], offB[FN];
#pragma unroll
  for (int mi = 0; mi < 4; mi++) {
    const int row = wm * 64 + mi * 16 + fr;
    offA[mi] = row * 32 + ((kq ^ ((row >> 1) & 3)) << 3);
  }
#pragma unroll
  for (int ni = 0; ni < FN; ni++) {
    const int row = wn * (BN / 2) + ni * 16 + fr;
    offB[ni] = row * 32 + ((kq ^ ((row >> 1) & 3)) << 3);
  }

  f32x4 acc[4][FN];
#pragma unroll
  for (int mi = 0; mi < 4; mi++)
#pragma unroll
    for (int ni = 0; ni < FN; ni++) acc[mi][ni] = (f32x4){0.f, 0.f, 0.f, 0.f};

  for (int k0 = 0; k0 < K; k0 += 32) {
    __syncthreads();
    gld16(Ap0 + k0, wA0);
    gld16(Ap1 + k0, wA1);
    gld16(Bp0 + k0, wB0);
    if constexpr (BN == 128) gld16(Bp1 + k0, wB1);
    __syncthreads();
    short8v a[4], b[FN];
#pragma unroll
    for (int mi = 0; mi < 4; mi++) a[mi] = *(const short8v*)&As[offA[mi]];
#pragma unroll
    for (int ni = 0; ni < FN; ni++) b[ni] = *(const short8v*)&Bs[offB[ni]];
#pragma unroll
    for (int mi = 0; mi < 4; mi++)
#pragma unroll
      for (int ni = 0; ni < FN; ni++)
        acc[mi][ni] = __builtin_amdgcn_mfma_f32_16x16x32_bf16(a[mi], b[ni], acc[mi][ni], 0, 0, 0);
  }

#pragma unroll
  for (int mi = 0; mi < 4; mi++) {
#pragma unroll
    for (int ni = 0; ni < FN; ni++) {
#pragma unroll
      for (int r = 0; r < 4; r++) {
        const int row = bm + wm * 64 + mi * 16 + (lane >> 4) * 4 + r;
        const int col = bn + wn * (BN / 2) + ni * 16 + fr;
        float v = acc[mi][ni][r];
        if (BIAS == 1) v += bias[row];
        if (BIAS == 2) v += bias[col];
        if (RELU) v = fmaxf(v, 0.f);
        const size_t idx = (size_t)(zC + (size_t)row * ldc + col);
        if (OUTF) Cf[idx] = v;
        if (OUTB) Cb[idx] = f2bf(v);
      }
    }
  }
}

// ---------------------------------------------------------------------------
// Online softmax over 256 entries at stride hStride, bf16 in -> bf16 out.
__global__ __launch_bounds__(256) void k_softmax_bf16(const ushort* __restrict__ E,
    ushort* __restrict__ Att, int outerStride, int hStride) {
  const size_t base = (size_t)blockIdx.x * outerStride + threadIdx.x;
  float m = -3.4e38f, s = 0.f;
  for (int h = 0; h < 256; h++) {
    const float x = bf2f(E[base + (size_t)h * hStride]);
    const float nm = fmaxf(m, x);
    s = s * __expf(m - nm) + __expf(x - nm);
    m = nm;
  }
  const float inv = 1.0f / s;
  for (int h = 0; h < 256; h++) {
    const size_t i = base + (size_t)h * hStride;
    Att[i] = f2bf(__expf(bf2f(E[i]) - m) * inv);
  }
}

// ---------------------------------------------------------------------------
// outF[c][h][w] = gamma*(O[c][h][w] + TH[c][w][h]) + CN[c][h][w]; O,TH bf16.
__global__ __launch_bounds__(256) void k_merge2(const ushort* __restrict__ O,
    const ushort* __restrict__ TH, const float* __restrict__ CN,
    const float* __restrict__ gammap, float* __restrict__ outF,
    ushort* __restrict__ outB) {
  __shared__ ushort t[32][34];
  const float g = *gammap;
  const size_t base = (size_t)blockIdx.z * HW;
  const int h0 = blockIdx.y << 5, w0 = blockIdx.x << 5;
  const int tx = threadIdx.x, ty = threadIdx.y;
#pragma unroll
  for (int r = 0; r < 32; r += 8)
    t[ty + r][tx] = TH[base + (w0 + ty + r) * SIDE + h0 + tx];
  __syncthreads();
#pragma unroll
  for (int r = 0; r < 32; r += 8) {
    const size_t idx = base + (h0 + ty + r) * SIDE + w0 + tx;
    const float v = g * (bf2f(O[idx]) + bf2f(t[tx][ty + r])) + CN[idx];
    outF[idx] = v;
    if (outB) outB[idx] = f2bf(v);
  }
}

// ---------------------------------------------------------------------------
__global__ __launch_bounds__(256) void k_logits(const float* __restrict__ X,
    const float* __restrict__ Wfc, const float* __restrict__ bfc,
    float* __restrict__ L) {
  const int n = blockIdx.x * 256 + threadIdx.x;
  float s = 0.f;
  for (int j = 0; j < 512; j++) s += X[(size_t)j * HW + n] * Wfc[j];
  L[n] = s + bfc[0];
}

__global__ __launch_bounds__(256) void k_smax_reduce(const float* __restrict__ L,
                                                     float* __restrict__ red) {
  __shared__ float sm[256];
  const int tid = threadIdx.x;
  float m = -3.4e38f;
  for (int i = tid; i < HW; i += 256) m = fmaxf(m, L[i]);
  sm[tid] = m;
  __syncthreads();
  for (int s = 128; s > 0; s >>= 1) {
    if (tid < s) sm[tid] = fmaxf(sm[tid], sm[tid + s]);
    __syncthreads();
  }
  const float M = sm[0];
  __syncthreads();
  float sum = 0.f;
  for (int i = tid; i < HW; i += 256) sum += expf(L[i] - M);
  sm[tid] = sum;
  __syncthreads();
  for (int s = 128; s > 0; s >>= 1) {
    if (tid < s) sm[tid] += sm[tid + s];
    __syncthreads();
  }
  if (tid == 0) { red[0] = M; red[1] = sm[0]; }
}

__global__ __launch_bounds__(256) void k_smax_write(const float* __restrict__ L,
    const float* __restrict__ red, float* __restrict__ out) {
  const int n = blockIdx.x * 256 + threadIdx.x;
  out[n] = expf(L[n] - red[0]) * (1.0f / red[1]);
}

__global__ void k_f2b(const float* __restrict__ in, ushort* __restrict__ out, int n) {
  const int i = blockIdx.x * 256 + threadIdx.x;
  if (i < n) out[i] = f2bf(in[i]);
}

__global__ void k_cpy(const float* __restrict__ a, float* __restrict__ b, int n) {
  const int i = blockIdx.x * 256 + threadIdx.x;
  if (i < n) b[i] = a[i];
}

// ---------------------------------------------------------------------------
extern "C" void kernel_launch(void* const* d_in, const int* in_sizes, int n_in,
                              void* d_out, int out_size, void* d_ws, size_t ws_size,
                              hipStream_t stream) {
  const float* h0 = (const float*)d_in[0];
  const float* w7 = (const float*)d_in[1];
  const float* b7 = (const float*)d_in[2];
  const float* w5 = (const float*)d_in[3];
  const float* b5 = (const float*)d_in[4];
  const float* w3 = (const float*)d_in[5];
  const float* b3 = (const float*)d_in[6];
  const float* W1 = (const float*)d_in[7];
  const float* b1 = (const float*)d_in[8];
  const float* Wq = (const float*)d_in[9];
  const float* bq = (const float*)d_in[10];
  const float* Wk = (const float*)d_in[11];
  const float* bk = (const float*)d_in[12];
  const float* Wv = (const float*)d_in[13];
  const float* bv = (const float*)d_in[14];
  const float* gamma = (const float*)d_in[15];
  const float* Wq1 = (const float*)d_in[16];
  const float* bq1 = (const float*)d_in[17];
  const float* Wk1 = (const float*)d_in[18];
  const float* bk1 = (const float*)d_in[19];
  const float* Wv1 = (const float*)d_in[20];
  const float* bv1 = (const float*)d_in[21];
  const float* gamma1 = (const float*)d_in[22];
  const float* Wfc = (const float*)d_in[23];
  const float* bfc = (const float*)d_in[24];

  char* W = (char*)d_ws;
  const size_t MB = 1 << 20;
  ushort* Xb    = (ushort*)(W + 0);          // [0,128) bf16 CHW conv input
  ushort* H2b   = (ushort*)(W + 0);          // [0,64) bf16 (after conv)
  ushort* H2t   = (ushort*)(W + 64 * MB);    // [64,128) bf16 act [n][512]
  ushort* qkt   = (ushort*)(W + 128 * MB);   // [128,144) bf16 [n][128]
  ushort* AttW  = (ushort*)(W + 144 * MB);   // [144,176)
  ushort* AttH  = (ushort*)(W + 176 * MB);   // [176,208)
  ushort* out1b = (ushort*)(W + 144 * MB);   // [144,208) transient (merge1)
  ushort* H1b   = (ushort*)(W + 256 * MB);   // [256,384) bf16 conv out CHW
  float*  H2f   = (float*)(W + 256 * MB);    // [256,384) fp32 residual, in-place
  ushort* H1t   = (ushort*)(W + 384 * MB);   // [384,512) bf16 [n][1024]
  ushort* Vb    = (ushort*)(W + 384 * MB);   // [384,448) bf16 (after H1t dead)
  ushort* vTb   = (ushort*)(W + 448 * MB);   // [448,512) bf16
  ushort* Ob    = (ushort*)(W + 512 * MB);   // [512,576) bf16 map-W out
  ushort* THbb  = (ushort*)(W + 576 * MB);   // [576,640) bf16 map-H out
  ushort* Eb    = (ushort*)(W + 640 * MB);   // [640,672) bf16 energies
  ushort* W1b   = (ushort*)(W + 704 * MB);
  ushort* Wvb   = (ushort*)(W + 705 * MB);
  ushort* Wv1b  = (ushort*)(W + 705 * MB + 512 * 1024);
  ushort* Wqkb  = (ushort*)(W + 706 * MB);
  ushort* Wqk1b = (ushort*)(W + 706 * MB + 128 * 1024);
  float*  wcomb = (float*)(W + 706 * MB + 256 * 1024);
  float*  bcomb = (float*)(W + 706 * MB + 464 * 1024);
  float*  bqk   = (float*)(W + 706 * MB + 472 * 1024);
  float*  bqk1  = (float*)(W + 706 * MB + 474 * 1024);
  float*  L     = (float*)(W + 707 * MB);
  float*  red   = (float*)(W + 707 * MB + 256 * 1024);

  // --- weight prep ---
  k_f2b<<<2048, 256, 0, stream>>>(W1, W1b, 512 * 1024);
  k_f2b<<<1024, 256, 0, stream>>>(Wv, Wvb, 256 * 1024);
  k_f2b<<<1024, 256, 0, stream>>>(Wv1, Wv1b, 256 * 1024);
  k_f2b<<<128, 256, 0, stream>>>(Wq, Wqkb, 32768);
  k_f2b<<<128, 256, 0, stream>>>(Wk, Wqkb + 32768, 32768);
  k_f2b<<<128, 256, 0, stream>>>(Wq1, Wqk1b, 32768);
  k_f2b<<<128, 256, 0, stream>>>(Wk1, Wqk1b + 32768, 32768);
  k_cpy<<<1, 256, 0, stream>>>(bq, bqk, 64);
  k_cpy<<<1, 256, 0, stream>>>(bk, bqk + 64, 64);
  k_cpy<<<1, 256, 0, stream>>>(bq1, bqk1, 64);
  k_cpy<<<1, 256, 0, stream>>>(bk1, bqk1 + 64, 64);
  k_wcomb<<<4, 256, 0, stream>>>(w7, b7, w5, b5, w3, b3, wcomb, bcomb);

  // --- PPEG ---
  k_transpose_nc<<<dim3(2048, 32), dim3(32, 8), 0, stream>>>(h0, Xb);
  k_dwconv7<<<dim3(4, 4, 1024), 256, 0, stream>>>(Xb, wcomb, bcomb, H1b);
  k_tr_u16<<<dim3(1024, 16, 1), 256, 0, stream>>>(H1b, H1t, 1024, HW, 0);

  // --- fc1 + ReLU ---
  k_mm<128, 1, 1, 1, 1><<<dim3(4, 512, 1), 256, 0, stream>>>(
      W1b, 1024, 0, H1t, 1024, 0, b1, H2f, H2b, HW, 0, 1024);
  k_tr_u16<<<dim3(1024, 8, 1), 256, 0, stream>>>(H2b, H2t, 512, HW, 0);

  auto cc_block = [&](const ushort* act, float* cnn, const ushort* Wqk_,
                      const float* bqk_, const ushort* Wv_, const float* bv_,
                      const float* gam, ushort* outB16) {
    k_mm<128, 2, 0, 0, 1><<<dim3(512, 1, 1), 256, 0, stream>>>(
        act, 512, 0, Wqk_, 512, 0, bqk_, nullptr, qkt, 128, 0, 512);
    k_mm<128, 1, 0, 0, 1><<<dim3(4, 512, 1), 256, 0, stream>>>(
        Wv_, 512, 0, act, 512, 0, bv_, nullptr, Vb, HW, 0, 512);
    k_tr_u16<<<dim3(4, 4, 512), 256, 0, stream>>>(Vb, vTb, 256, 256, 65536);
    // W path (rows, batch h): E[h][w][v], softmax over h (stride HW)
    k_mm<128, 0, 0, 0, 1><<<dim3(2, 2, 256), 256, 0, stream>>>(
        qkt, 128, 32768, qkt + 64, 128, 32768, nullptr, nullptr, Eb, 256, 65536, 64);
    k_softmax_bf16<<<256, 256, 0, stream>>>(Eb, AttW, 256, HW);
    k_mm<128, 0, 0, 0, 1><<<dim3(4, 2, 256), 256, 0, stream>>>(
        Vb, HW, 256, AttW, 256, 65536, nullptr, nullptr, Ob, HW, 256, 256);
    // H path (cols, batch w): E[w][h][g], softmax over h (stride 256)
    k_mm<128, 0, 0, 0, 1><<<dim3(2, 2, 256), 256, 0, stream>>>(
        qkt, 32768, 128, qkt + 64, 32768, 128, nullptr, nullptr, Eb, 256, 65536, 64);
    k_softmax_bf16<<<256, 256, 0, stream>>>(Eb, AttH, HW, 256);
    k_mm<128, 0, 0, 0, 1><<<dim3(4, 2, 256), 256, 0, stream>>>(
        vTb, HW, 256, AttH, 256, 65536, nullptr, nullptr, THbb, HW, 256, 256);
    k_merge2<<<dim3(8, 8, 512), dim3(32, 8), 0, stream>>>(
        Ob, THbb, cnn, gam, cnn, outB16);
  };

  cc_block(H2t, H2f, Wqkb, bqk, Wvb, bv, gamma, out1b);
  k_tr_u16<<<dim3(1024, 8, 1), 256, 0, stream>>>(out1b, H2t, 512, HW, 0);
  cc_block(H2t, H2f, Wqk1b, bqk1, Wv1b, bv1, gamma1, nullptr);

  // --- final fc + instance softmax ---
  k_logits<<<256, 256, 0, stream>>>(H2f, Wfc, bfc, L);
  k_smax_reduce<<<1, 256, 0, stream>>>(L, red);
  k_smax_write<<<256, 256, 0, stream>>>(L, red, (float*)d_out);
}

// Round 5
// 1401.210 us; speedup vs baseline: 3.5645x; 1.1394x over previous
//
#include <hip/hip_runtime.h>

#define HW 65536
#define SIDE 256

typedef __attribute__((ext_vector_type(8))) short short8v;
typedef __attribute__((ext_vector_type(4))) float f32x4;

__device__ __forceinline__ ushort f2bf(float f) {
  unsigned int u = __builtin_bit_cast(unsigned int, f);
  u = (u + 0x7fff + ((u >> 16) & 1)) >> 16;
  return (ushort)u;
}
__device__ __forceinline__ float bf2f(unsigned int u) {
  return __builtin_bit_cast(float, (u & 0xffffu) << 16);
}
__device__ __forceinline__ void gld16(const void* g, void* l) {
  __builtin_amdgcn_global_load_lds(
      (const __attribute__((address_space(1))) void*)g,
      (__attribute__((address_space(3))) void*)l, 16, 0, 0);
}

// ---------------------------------------------------------------------------
// Transpose h0 [N=65536][C=1024] fp32 -> X [C][N] bf16
__global__ __launch_bounds__(256) void k_transpose_nc(const float* __restrict__ in,
                                                      ushort* __restrict__ out) {
  __shared__ float t[32][33];
  const int n0 = blockIdx.x << 5, c0 = blockIdx.y << 5;
  const int tx = threadIdx.x, ty = threadIdx.y;
#pragma unroll
  for (int r = 0; r < 32; r += 8)
    t[ty + r][tx] = in[(size_t)(n0 + ty + r) * 1024 + c0 + tx];
  __syncthreads();
#pragma unroll
  for (int r = 0; r < 32; r += 8)
    out[(size_t)(c0 + ty + r) * HW + n0 + tx] = f2bf(t[tx][ty + r]);
}

// ---------------------------------------------------------------------------
__global__ __launch_bounds__(256) void k_wcomb(const float* __restrict__ w7,
    const float* __restrict__ b7, const float* __restrict__ w5,
    const float* __restrict__ b5, const float* __restrict__ w3,
    const float* __restrict__ b3, float* __restrict__ wc, float* __restrict__ bc) {
  const int c = blockIdx.x * 256 + threadIdx.x;
  if (c >= 1024) return;
  float w[49];
#pragma unroll
  for (int i = 0; i < 49; i++) w[i] = w7[c * 49 + i];
  for (int dy = 0; dy < 5; dy++)
    for (int dx = 0; dx < 5; dx++)
      w[(dy + 1) * 7 + (dx + 1)] += w5[c * 25 + dy * 5 + dx];
  for (int dy = 0; dy < 3; dy++)
    for (int dx = 0; dx < 3; dx++)
      w[(dy + 2) * 7 + (dx + 2)] += w3[c * 9 + dy * 3 + dx];
  w[3 * 7 + 3] += 1.0f;
#pragma unroll
  for (int i = 0; i < 49; i++) wc[c * 49 + i] = w[i];
  bc[c] = b7[c] + b5[c] + b3[c];
}

// ---------------------------------------------------------------------------
// Depthwise 7x7 conv, CHW, bf16 in -> fp32 compute -> bf16 out.
// grid (8 stripes, 1024 ch), block 256. Full-width 32-row stripe per block.
// LDS tile rows y0-3..y0+34 (38), cols: image col c at idx c+4 (halo zeroed).
// Staging: uint2 (4 bf16) per lane -> one aligned ds_write_b128, consecutive
// 16B across lanes (conflict-free), no div/mod. Compute: rolling 14 window
// rows, 3x ds_read_b128 each (64-lane consecutive => conflict-free),
// weights via uniform (scalar) loads.
__global__ __launch_bounds__(256) void k_dwconv7(const ushort* __restrict__ X,
    const float* __restrict__ wc, const float* __restrict__ bc,
    ushort* __restrict__ out) {
  __shared__ float tile[38][264];
  const int c = blockIdx.y;
  const int y0 = blockIdx.x << 5;
  const int tid = threadIdx.x;
  const ushort* Xc = X + (size_t)c * HW;

  float w[49];
#pragma unroll
  for (int i = 0; i < 49; i++) w[i] = wc[c * 49 + i];
  const float bcv = bc[c];

  // zero halo cols (idx 0..3 and 260..263)
  for (int i = tid; i < 38 * 8; i += 256) {
    const int r = i >> 3, cc = i & 7;
    tile[r][cc < 4 ? cc : 256 + cc] = 0.f;
  }
  // stage 38 rows x 256 cols
  for (int i = tid; i < 38 * 64; i += 256) {
    const int r = i >> 6, j4 = i & 63;
    const int y = y0 - 3 + r;
    float4 f = {0.f, 0.f, 0.f, 0.f};
    if (y >= 0 && y < SIDE) {
      const uint2 u = *(const uint2*)(Xc + y * SIDE + (j4 << 2));
      f.x = bf2f(u.x); f.y = bf2f(u.x >> 16);
      f.z = bf2f(u.y); f.w = bf2f(u.y >> 16);
    }
    *(float4*)&tile[r][(j4 << 2) + 4] = f;
  }
  __syncthreads();

  const int lx = (tid & 63) << 2;   // output cols lx..lx+3
  const int ry = (tid >> 6) << 3;   // output rows ry..ry+7 within stripe
  float acc[8][4] = {};
#pragma unroll
  for (int r = 0; r < 14; r++) {
    float rv[12];
    *(float4*)&rv[0] = *(const float4*)&tile[ry + r][lx];
    *(float4*)&rv[4] = *(const float4*)&tile[ry + r][lx + 4];
    *(float4*)&rv[8] = *(const float4*)&tile[ry + r][lx + 8];
#pragma unroll
    for (int m = 0; m < 8; m++) {
      const int dy = r - m;
      if (dy < 0 || dy > 6) continue;
#pragma unroll
      for (int dx = 0; dx < 7; dx++) {
        const float ww = w[dy * 7 + dx];
#pragma unroll
        for (int o = 0; o < 4; o++) acc[m][o] += ww * rv[o + 1 + dx];
      }
    }
  }
#pragma unroll
  for (int m = 0; m < 8; m++) {
    ushort4 o4 = {f2bf(acc[m][0] + bcv), f2bf(acc[m][1] + bcv),
                  f2bf(acc[m][2] + bcv), f2bf(acc[m][3] + bcv)};
    *(ushort4*)&out[(size_t)c * HW + (y0 + ry + m) * SIDE + lx] = o4;
  }
}

// ---------------------------------------------------------------------------
// Generic batched ushort (bf16) transpose: in [R][C] -> out [C][R].
__global__ __launch_bounds__(256) void k_tr_u16(const ushort* __restrict__ in,
    ushort* __restrict__ out, int R, int C, long long bs) {
  __shared__ ushort t[64][66];
  const size_t base = (size_t)blockIdx.z * bs;
  const int c0 = blockIdx.x << 6, r0 = blockIdx.y << 6;
  const int tx = threadIdx.x & 63, ty = threadIdx.x >> 6;
#pragma unroll
  for (int i = 0; i < 64; i += 4)
    t[ty + i][tx] = in[base + (size_t)(r0 + ty + i) * C + c0 + tx];
  __syncthreads();
#pragma unroll
  for (int i = 0; i < 64; i += 4)
    out[base + (size_t)(c0 + ty + i) * R + r0 + tx] = t[tx][ty + i];
}

// ---------------------------------------------------------------------------
// bf16 MFMA GEMM:  C[m][n] = sum_k A[m][k] * B[n][k]  (both K-contiguous)
// 128x128 tile, BK=32, 4 waves, global_load_lds staging (pre-swizzled source,
// linear LDS dest; XOR-swizzled fragment reads).
template <int BN, int BIAS, int RELU, int OUTF, int OUTB>
__global__ __launch_bounds__(256) void k_mm(
    const ushort* __restrict__ A, int lda, long long bsA,
    const ushort* __restrict__ B, int ldb, long long bsB,
    const float* __restrict__ bias,
    float* __restrict__ Cf, ushort* __restrict__ Cb, int ldc, long long bsC,
    int K) {
  static_assert(BN == 64 || BN == 128, "BN");
  constexpr int FN = BN / 32;
  __shared__ __align__(16) ushort As[128 * 32];
  __shared__ __align__(16) ushort Bs[BN * 32];
  const int tid = threadIdx.x;
  const int bm = blockIdx.x << 7, bn = blockIdx.y * BN;
  const long long zA = (long long)blockIdx.z * bsA;
  const long long zB = (long long)blockIdx.z * bsB;
  const long long zC = (long long)blockIdx.z * bsC;

  const int sr = tid >> 2, sq = tid & 3;
  const int sw0 = (sr >> 1) & 3;
  const int sw1 = ((sr + 64) >> 1) & 3;
  const ushort* Ap0 = A + zA + (size_t)(bm + sr) * lda + ((sq ^ sw0) << 3);
  const ushort* Ap1 = A + zA + (size_t)(bm + sr + 64) * lda + ((sq ^ sw1) << 3);
  const ushort* Bp0 = B + zB + (size_t)(bn + sr) * ldb + ((sq ^ sw0) << 3);
  const ushort* Bp1 = nullptr;
  if constexpr (BN == 128)
    Bp1 = B + zB + (size_t)(bn + sr + 64) * ldb + ((sq ^ sw1) << 3);
  ushort* wA0 = &As[sr * 32 + sq * 8];
  ushort* wA1 = &As[(sr + 64) * 32 + sq * 8];
  ushort* wB0 = &Bs[sr * 32 + sq * 8];
  ushort* wB1 = nullptr;
  if constexpr (BN == 128) wB1 = &Bs[(sr + 64) * 32 + sq * 8];

  const int lane = tid & 63, wv = tid >> 6;
  const int wm = wv & 1, wn = wv >> 1;
  const int fr = lane & 15, kq = lane >> 4;
  int offA[4], offB[FN];
#pragma unroll
  for (int mi = 0; mi < 4; mi++) {
    const int row = wm * 64 + mi * 16 + fr;
    offA[mi] = row * 32 + ((kq ^ ((row >> 1) & 3)) << 3);
  }
#pragma unroll
  for (int ni = 0; ni < FN; ni++) {
    const int row = wn * (BN / 2) + ni * 16 + fr;
    offB[ni] = row * 32 + ((kq ^ ((row >> 1) & 3)) << 3);
  }

  f32x4 acc[4][FN];
#pragma unroll
  for (int mi = 0; mi < 4; mi++)
#pragma unroll
    for (int ni = 0; ni < FN; ni++) acc[mi][ni] = (f32x4){0.f, 0.f, 0.f, 0.f};

  for (int k0 = 0; k0 < K; k0 += 32) {
    __syncthreads();
    gld16(Ap0 + k0, wA0);
    gld16(Ap1 + k0, wA1);
    gld16(Bp0 + k0, wB0);
    if constexpr (BN == 128) gld16(Bp1 + k0, wB1);
    __syncthreads();
    short8v a[4], b[FN];
#pragma unroll
    for (int mi = 0; mi < 4; mi++) a[mi] = *(const short8v*)&As[offA[mi]];
#pragma unroll
    for (int ni = 0; ni < FN; ni++) b[ni] = *(const short8v*)&Bs[offB[ni]];
#pragma unroll
    for (int mi = 0; mi < 4; mi++)
#pragma unroll
      for (int ni = 0; ni < FN; ni++)
        acc[mi][ni] = __builtin_amdgcn_mfma_f32_16x16x32_bf16(a[mi], b[ni], acc[mi][ni], 0, 0, 0);
  }

#pragma unroll
  for (int mi = 0; mi < 4; mi++) {
#pragma unroll
    for (int ni = 0; ni < FN; ni++) {
#pragma unroll
      for (int r = 0; r < 4; r++) {
        const int row = bm + wm * 64 + mi * 16 + (lane >> 4) * 4 + r;
        const int col = bn + wn * (BN / 2) + ni * 16 + fr;
        float v = acc[mi][ni][r];
        if (BIAS == 1) v += bias[row];
        if (BIAS == 2) v += bias[col];
        if (RELU) v = fmaxf(v, 0.f);
        const size_t idx = (size_t)(zC + (size_t)row * ldc + col);
        if (OUTF) Cf[idx] = v;
        if (OUTB) Cb[idx] = f2bf(v);
      }
    }
  }
}

// ---------------------------------------------------------------------------
// Online softmax over 256 entries at stride hStride, bf16 in -> bf16 out.
__global__ __launch_bounds__(256) void k_softmax_bf16(const ushort* __restrict__ E,
    ushort* __restrict__ Att, int outerStride, int hStride) {
  const size_t base = (size_t)blockIdx.x * outerStride + threadIdx.x;
  float m = -3.4e38f, s = 0.f;
  for (int h = 0; h < 256; h++) {
    const float x = bf2f(E[base + (size_t)h * hStride]);
    const float nm = fmaxf(m, x);
    s = s * __expf(m - nm) + __expf(x - nm);
    m = nm;
  }
  const float inv = 1.0f / s;
  for (int h = 0; h < 256; h++) {
    const size_t i = base + (size_t)h * hStride;
    Att[i] = f2bf(__expf(bf2f(E[i]) - m) * inv);
  }
}

// ---------------------------------------------------------------------------
// outB[c][h][w] = f2bf( g*(O[c][h][w] + TH[c][w][h]) + CN[c][h][w] )
// all bf16; outB may alias CN (same-index read-then-write, race-free).
__global__ __launch_bounds__(256) void k_merge2(const ushort* __restrict__ O,
    const ushort* __restrict__ TH, const ushort* __restrict__ CN,
    const float* __restrict__ gammap, ushort* __restrict__ outB) {
  __shared__ ushort t[32][34];
  const float g = *gammap;
  const size_t base = (size_t)blockIdx.z * HW;
  const int h0 = blockIdx.y << 5, w0 = blockIdx.x << 5;
  const int tx = threadIdx.x, ty = threadIdx.y;
#pragma unroll
  for (int r = 0; r < 32; r += 8)
    t[ty + r][tx] = TH[base + (w0 + ty + r) * SIDE + h0 + tx];
  __syncthreads();
#pragma unroll
  for (int r = 0; r < 32; r += 8) {
    const size_t idx = base + (h0 + ty + r) * SIDE + w0 + tx;
    const float v = g * (bf2f(O[idx]) + bf2f(t[tx][ty + r])) + bf2f(CN[idx]);
    outB[idx] = f2bf(v);
  }
}

// ---------------------------------------------------------------------------
// logits[n] = sum_j bf2f(X[j][n])*Wfc[j] + bfc
__global__ __launch_bounds__(256) void k_logits(const ushort* __restrict__ X,
    const float* __restrict__ Wfc, const float* __restrict__ bfc,
    float* __restrict__ L) {
  const int n = blockIdx.x * 256 + threadIdx.x;
  float s = 0.f;
  for (int j = 0; j < 512; j++) s += bf2f(X[(size_t)j * HW + n]) * Wfc[j];
  L[n] = s + bfc[0];
}

__global__ __launch_bounds__(256) void k_smax_reduce(const float* __restrict__ L,
                                                     float* __restrict__ red) {
  __shared__ float sm[256];
  const int tid = threadIdx.x;
  float m = -3.4e38f;
  for (int i = tid; i < HW; i += 256) m = fmaxf(m, L[i]);
  sm[tid] = m;
  __syncthreads();
  for (int s = 128; s > 0; s >>= 1) {
    if (tid < s) sm[tid] = fmaxf(sm[tid], sm[tid + s]);
    __syncthreads();
  }
  const float M = sm[0];
  __syncthreads();
  float sum = 0.f;
  for (int i = tid; i < HW; i += 256) sum += expf(L[i] - M);
  sm[tid] = sum;
  __syncthreads();
  for (int s = 128; s > 0; s >>= 1) {
    if (tid < s) sm[tid] += sm[tid + s];
    __syncthreads();
  }
  if (tid == 0) { red[0] = M; red[1] = sm[0]; }
}

__global__ __launch_bounds__(256) void k_smax_write(const float* __restrict__ L,
    const float* __restrict__ red, float* __restrict__ out) {
  const int n = blockIdx.x * 256 + threadIdx.x;
  out[n] = expf(L[n] - red[0]) * (1.0f / red[1]);
}

__global__ void k_f2b(const float* __restrict__ in, ushort* __restrict__ out, int n) {
  const int i = blockIdx.x * 256 + threadIdx.x;
  if (i < n) out[i] = f2bf(in[i]);
}

__global__ void k_cpy(const float* __restrict__ a, float* __restrict__ b, int n) {
  const int i = blockIdx.x * 256 + threadIdx.x;
  if (i < n) b[i] = a[i];
}

// ---------------------------------------------------------------------------
extern "C" void kernel_launch(void* const* d_in, const int* in_sizes, int n_in,
                              void* d_out, int out_size, void* d_ws, size_t ws_size,
                              hipStream_t stream) {
  const float* h0 = (const float*)d_in[0];
  const float* w7 = (const float*)d_in[1];
  const float* b7 = (const float*)d_in[2];
  const float* w5 = (const float*)d_in[3];
  const float* b5 = (const float*)d_in[4];
  const float* w3 = (const float*)d_in[5];
  const float* b3 = (const float*)d_in[6];
  const float* W1 = (const float*)d_in[7];
  const float* b1 = (const float*)d_in[8];
  const float* Wq = (const float*)d_in[9];
  const float* bq = (const float*)d_in[10];
  const float* Wk = (const float*)d_in[11];
  const float* bk = (const float*)d_in[12];
  const float* Wv = (const float*)d_in[13];
  const float* bv = (const float*)d_in[14];
  const float* gamma = (const float*)d_in[15];
  const float* Wq1 = (const float*)d_in[16];
  const float* bq1 = (const float*)d_in[17];
  const float* Wk1 = (const float*)d_in[18];
  const float* bk1 = (const float*)d_in[19];
  const float* Wv1 = (const float*)d_in[20];
  const float* bv1 = (const float*)d_in[21];
  const float* gamma1 = (const float*)d_in[22];
  const float* Wfc = (const float*)d_in[23];
  const float* bfc = (const float*)d_in[24];

  char* W = (char*)d_ws;
  const size_t MB = 1 << 20;
  ushort* Xb    = (ushort*)(W + 0);          // [0,128) bf16 CHW conv input
  ushort* H2b   = (ushort*)(W + 0);          // [0,64) bf16 h2/out1/out2 CHW
  ushort* H2t   = (ushort*)(W + 64 * MB);    // [64,128) bf16 act [n][512]
  ushort* qkt   = (ushort*)(W + 128 * MB);   // [128,144) bf16 [n][128]
  ushort* AttW  = (ushort*)(W + 144 * MB);   // [144,176)
  ushort* AttH  = (ushort*)(W + 176 * MB);   // [176,208)
  ushort* H1b   = (ushort*)(W + 256 * MB);   // [256,384) bf16 conv out CHW
  ushort* H1t   = (ushort*)(W + 384 * MB);   // [384,512) bf16 [n][1024]
  ushort* Vb    = (ushort*)(W + 384 * MB);   // [384,448) bf16 (after H1t dead)
  ushort* vTb   = (ushort*)(W + 448 * MB);   // [448,512) bf16
  ushort* Ob    = (ushort*)(W + 512 * MB);   // [512,576) bf16 map-W out
  ushort* THbb  = (ushort*)(W + 576 * MB);   // [576,640) bf16 map-H out
  ushort* Eb    = (ushort*)(W + 640 * MB);   // [640,672) bf16 energies
  ushort* W1b   = (ushort*)(W + 704 * MB);
  ushort* Wvb   = (ushort*)(W + 705 * MB);
  ushort* Wv1b  = (ushort*)(W + 705 * MB + 512 * 1024);
  ushort* Wqkb  = (ushort*)(W + 706 * MB);
  ushort* Wqk1b = (ushort*)(W + 706 * MB + 128 * 1024);
  float*  wcomb = (float*)(W + 706 * MB + 256 * 1024);
  float*  bcomb = (float*)(W + 706 * MB + 464 * 1024);
  float*  bqk   = (float*)(W + 706 * MB + 472 * 1024);
  float*  bqk1  = (float*)(W + 706 * MB + 474 * 1024);
  float*  L     = (float*)(W + 707 * MB);
  float*  red   = (float*)(W + 707 * MB + 256 * 1024);

  // --- weight prep ---
  k_f2b<<<2048, 256, 0, stream>>>(W1, W1b, 512 * 1024);
  k_f2b<<<1024, 256, 0, stream>>>(Wv, Wvb, 256 * 1024);
  k_f2b<<<1024, 256, 0, stream>>>(Wv1, Wv1b, 256 * 1024);
  k_f2b<<<128, 256, 0, stream>>>(Wq, Wqkb, 32768);
  k_f2b<<<128, 256, 0, stream>>>(Wk, Wqkb + 32768, 32768);
  k_f2b<<<128, 256, 0, stream>>>(Wq1, Wqk1b, 32768);
  k_f2b<<<128, 256, 0, stream>>>(Wk1, Wqk1b + 32768, 32768);
  k_cpy<<<1, 256, 0, stream>>>(bq, bqk, 64);
  k_cpy<<<1, 256, 0, stream>>>(bk, bqk + 64, 64);
  k_cpy<<<1, 256, 0, stream>>>(bq1, bqk1, 64);
  k_cpy<<<1, 256, 0, stream>>>(bk1, bqk1 + 64, 64);
  k_wcomb<<<4, 256, 0, stream>>>(w7, b7, w5, b5, w3, b3, wcomb, bcomb);

  // --- PPEG ---
  k_transpose_nc<<<dim3(2048, 32), dim3(32, 8), 0, stream>>>(h0, Xb);
  k_dwconv7<<<dim3(8, 1024), 256, 0, stream>>>(Xb, wcomb, bcomb, H1b);
  k_tr_u16<<<dim3(1024, 16, 1), 256, 0, stream>>>(H1b, H1t, 1024, HW, 0);

  // --- fc1 + ReLU (bf16 out only) ---
  k_mm<128, 1, 1, 0, 1><<<dim3(4, 512, 1), 256, 0, stream>>>(
      W1b, 1024, 0, H1t, 1024, 0, b1, nullptr, H2b, HW, 0, 1024);
  k_tr_u16<<<dim3(1024, 8, 1), 256, 0, stream>>>(H2b, H2t, 512, HW, 0);

  auto cc_block = [&](const ushort* act, ushort* cnn, const ushort* Wqk_,
                      const float* bqk_, const ushort* Wv_, const float* bv_,
                      const float* gam) {
    k_mm<128, 2, 0, 0, 1><<<dim3(512, 1, 1), 256, 0, stream>>>(
        act, 512, 0, Wqk_, 512, 0, bqk_, nullptr, qkt, 128, 0, 512);
    k_mm<128, 1, 0, 0, 1><<<dim3(4, 512, 1), 256, 0, stream>>>(
        Wv_, 512, 0, act, 512, 0, bv_, nullptr, Vb, HW, 0, 512);
    k_tr_u16<<<dim3(4, 4, 512), 256, 0, stream>>>(Vb, vTb, 256, 256, 65536);
    // W path (rows, batch h): E[h][w][v], softmax over h (stride HW)
    k_mm<128, 0, 0, 0, 1><<<dim3(2, 2, 256), 256, 0, stream>>>(
        qkt, 128, 32768, qkt + 64, 128, 32768, nullptr, nullptr, Eb, 256, 65536, 64);
    k_softmax_bf16<<<256, 256, 0, stream>>>(Eb, AttW, 256, HW);
    k_mm<128, 0, 0, 0, 1><<<dim3(4, 2, 256), 256, 0, stream>>>(
        Vb, HW, 256, AttW, 256, 65536, nullptr, nullptr, Ob, HW, 256, 256);
    // H path (cols, batch w): E[w][h][g], softmax over h (stride 256)
    k_mm<128, 0, 0, 0, 1><<<dim3(2, 2, 256), 256, 0, stream>>>(
        qkt, 32768, 128, qkt + 64, 32768, 128, nullptr, nullptr, Eb, 256, 65536, 64);
    k_softmax_bf16<<<256, 256, 0, stream>>>(Eb, AttH, HW, 256);
    k_mm<128, 0, 0, 0, 1><<<dim3(4, 2, 256), 256, 0, stream>>>(
        vTb, HW, 256, AttH, 256, 65536, nullptr, nullptr, THbb, HW, 256, 256);
    // out = gamma*(O + TH^T) + cnn  (bf16 in-place over cnn)
    k_merge2<<<dim3(8, 8, 512), dim3(32, 8), 0, stream>>>(
        Ob, THbb, cnn, gam, cnn);
  };

  cc_block(H2t, H2b, Wqkb, bqk, Wvb, bv, gamma);
  k_tr_u16<<<dim3(1024, 8, 1), 256, 0, stream>>>(H2b, H2t, 512, HW, 0);
  cc_block(H2t, H2b, Wqk1b, bqk1, Wv1b, bv1, gamma1);

  // --- final fc + instance softmax ---
  k_logits<<<256, 256, 0, stream>>>(H2b, Wfc, bfc, L);
  k_smax_reduce<<<1, 256, 0, stream>>>(L, red);
  k_smax_write<<<256, 256, 0, stream>>>(L, red, (float*)d_out);
}